// Round 2
// baseline (445.114 us; speedup 1.0000x reference)
//
#include <hip/hip_runtime.h>

// GCNConv: out = A_hat @ x @ W + b, A_hat = D^-1/2 (A + I) D^-1/2
// Strategy: CSR counting-sort by dst -> per-node wave gather-aggregate of x
// into d_out, then in-place register-blocked GEMM (x W + b) on d_out.
// NOTE: harness delivers ALL integer inputs as int32 (edge_index included).

#define SCAN_T 256
#define SCAN_E 1024   // elements scanned per block (4/thread)
#define WPB 4         // nodes (waves) per block in aggregate

__global__ void k_init(int* __restrict__ cnt, int* __restrict__ cursor, int n) {
  int i = blockIdx.x * blockDim.x + threadIdx.x;
  if (i < n) { cnt[i] = 0; cursor[i] = 0; }
}

__global__ void k_count(const int* __restrict__ ei, int* __restrict__ cnt, int E) {
  int e = blockIdx.x * blockDim.x + threadIdx.x;
  if (e < E) {
    int dst = ei[E + e];
    atomicAdd(&cnt[dst], 1);
  }
}

__global__ void k_scan_local(const int* __restrict__ cnt, int* __restrict__ offs,
                             int* __restrict__ bsums, int n) {
  __shared__ int sh[SCAN_T];
  int t = threadIdx.x;
  int base = blockIdx.x * SCAN_E + t * 4;
  int v0 = 0, v1 = 0, v2 = 0, v3 = 0;
  if (base + 0 < n) v0 = cnt[base + 0];
  if (base + 1 < n) v1 = cnt[base + 1];
  if (base + 2 < n) v2 = cnt[base + 2];
  if (base + 3 < n) v3 = cnt[base + 3];
  int sum = v0 + v1 + v2 + v3;
  sh[t] = sum;
  __syncthreads();
  for (int d = 1; d < SCAN_T; d <<= 1) {
    int xv = (t >= d) ? sh[t - d] : 0;
    __syncthreads();
    sh[t] += xv;
    __syncthreads();
  }
  int run = sh[t] - sum;  // exclusive prefix of this thread's 4 elems
  if (base + 0 < n) offs[base + 0] = run; run += v0;
  if (base + 1 < n) offs[base + 1] = run; run += v1;
  if (base + 2 < n) offs[base + 2] = run; run += v2;
  if (base + 3 < n) offs[base + 3] = run;
  if (t == SCAN_T - 1) bsums[blockIdx.x] = sh[t];
}

__global__ void k_scan_bsums(int* __restrict__ bsums, int nb) {
  __shared__ int sh[SCAN_T];
  int t = threadIdx.x;
  int v = (t < nb) ? bsums[t] : 0;
  sh[t] = v;
  __syncthreads();
  for (int d = 1; d < SCAN_T; d <<= 1) {
    int xv = (t >= d) ? sh[t - d] : 0;
    __syncthreads();
    sh[t] += xv;
    __syncthreads();
  }
  if (t < nb) bsums[t] = sh[t] - v;  // exclusive
}

__global__ void k_scan_add_dinv(int* __restrict__ offs, const int* __restrict__ bsums,
                                const int* __restrict__ cnt, float* __restrict__ dinv, int n) {
  int i = blockIdx.x * blockDim.x + threadIdx.x;
  if (i < n) {
    offs[i] += bsums[i / SCAN_E];
    dinv[i] = rsqrtf((float)cnt[i] + 1.0f);  // deg includes self loop
  }
}

__global__ void k_fill(const int* __restrict__ ei, const int* __restrict__ offs,
                       int* __restrict__ cursor, int* __restrict__ csr, int E) {
  int e = blockIdx.x * blockDim.x + threadIdx.x;
  if (e < E) {
    int src = ei[e];
    int dst = ei[E + e];
    int slot = offs[dst] + atomicAdd(&cursor[dst], 1);
    csr[slot] = src;
  }
}

// One wave (64 lanes) per node; each lane owns 2 consecutive channels (float2).
__global__ void __launch_bounds__(256) k_aggregate(
    const float* __restrict__ x, const float* __restrict__ dinv,
    const int* __restrict__ offs, const int* __restrict__ cnt,
    const int* __restrict__ csr, float* __restrict__ out, int n) {
  int node = blockIdx.x * WPB + (threadIdx.x >> 6);
  int lane = threadIdx.x & 63;
  if (node >= n) return;
  const float2* __restrict__ x2 = (const float2*)x;
  float di = dinv[node];
  float2 self = x2[(size_t)node * 64 + lane];
  float sw = di * di;  // self-loop norm
  float ax = self.x * sw, ay = self.y * sw;
  int s = offs[node];
  int end = s + cnt[node];
  for (; s + 4 <= end; s += 4) {
    int i0 = csr[s + 0], i1 = csr[s + 1], i2 = csr[s + 2], i3 = csr[s + 3];
    float2 a0 = x2[(size_t)i0 * 64 + lane];
    float2 a1 = x2[(size_t)i1 * 64 + lane];
    float2 a2 = x2[(size_t)i2 * 64 + lane];
    float2 a3 = x2[(size_t)i3 * 64 + lane];
    float w0 = dinv[i0] * di, w1 = dinv[i1] * di, w2 = dinv[i2] * di, w3 = dinv[i3] * di;
    ax = fmaf(a0.x, w0, ax); ay = fmaf(a0.y, w0, ay);
    ax = fmaf(a1.x, w1, ax); ay = fmaf(a1.y, w1, ay);
    ax = fmaf(a2.x, w2, ax); ay = fmaf(a2.y, w2, ay);
    ax = fmaf(a3.x, w3, ax); ay = fmaf(a3.y, w3, ay);
  }
  for (; s < end; ++s) {
    int i0 = csr[s];
    float2 a0 = x2[(size_t)i0 * 64 + lane];
    float w0 = dinv[i0] * di;
    ax = fmaf(a0.x, w0, ax); ay = fmaf(a0.y, w0, ay);
  }
  float2 r; r.x = ax; r.y = ay;
  ((float2*)out)[(size_t)node * 64 + lane] = r;
}

// ---- Fallback (small ws): atomic scatter-aggregate ----
__global__ void k_deg_init(int* __restrict__ deg, int n) {
  int i = blockIdx.x * blockDim.x + threadIdx.x;
  if (i < n) deg[i] = 0;
}
__global__ void k_dinv_only(const int* __restrict__ deg, float* __restrict__ dinv, int n) {
  int i = blockIdx.x * blockDim.x + threadIdx.x;
  if (i < n) dinv[i] = rsqrtf((float)deg[i] + 1.0f);
}
__global__ void k_self_init(const float* __restrict__ x, const float* __restrict__ dinv,
                            float* __restrict__ out, int n) {
  int i = blockIdx.x * blockDim.x + threadIdx.x;  // one thread per float4 group
  int node = i >> 5, cg = i & 31;
  if (node >= n) return;
  float w = dinv[node]; w *= w;
  float4 v = ((const float4*)x)[(size_t)node * 32 + cg];
  v.x *= w; v.y *= w; v.z *= w; v.w *= w;
  ((float4*)out)[(size_t)node * 32 + cg] = v;
}
__global__ void k_scatter(const int* __restrict__ ei, const float* __restrict__ x,
                          const float* __restrict__ dinv, float* __restrict__ out, int E) {
  int i = blockIdx.x * blockDim.x + threadIdx.x;  // one thread per (edge, float4 group)
  int e = i >> 5, cg = i & 31;
  if (e >= E) return;
  int src = ei[e], dst = ei[E + e];
  float w = dinv[src] * dinv[dst];
  float4 v = ((const float4*)x)[(size_t)src * 32 + cg];
  float* o = out + (size_t)dst * 128 + cg * 4;
  atomicAdd(o + 0, v.x * w);
  atomicAdd(o + 1, v.y * w);
  atomicAdd(o + 2, v.z * w);
  atomicAdd(o + 3, v.w * w);
}

// In-place GEMM: io[64 rows x 128] = io @ W + b. Each block owns 64 rows,
// stages them in LDS, so in-place is safe. Thread tile: 4 rows x 8 cols.
__global__ void __launch_bounds__(256) k_gemm_bias(
    float* __restrict__ io, const float* __restrict__ Wm,
    const float* __restrict__ bias, int n) {
  __shared__ float xs[64][129];   // [row][k], padded
  __shared__ float Bs[32][128];   // k-chunk of W, [k][col]
  int t = threadIdx.x;
  int r0 = blockIdx.x * 64;

  for (int f = t * 4; f < 64 * 128; f += 1024) {
    int row = f >> 7, col = f & 127;
    float4 v = make_float4(0.f, 0.f, 0.f, 0.f);
    if (r0 + row < n) v = *(const float4*)(io + (size_t)(r0 + row) * 128 + col);
    xs[row][col + 0] = v.x; xs[row][col + 1] = v.y;
    xs[row][col + 2] = v.z; xs[row][col + 3] = v.w;
  }

  int tx = t & 15;   // col group: cols tx*8..tx*8+7
  int ty = t >> 4;   // row group: rows ty*4..ty*4+3
  float acc[4][8];
#pragma unroll
  for (int r = 0; r < 4; ++r)
#pragma unroll
    for (int c = 0; c < 8; ++c) acc[r][c] = 0.f;

  for (int kc = 0; kc < 128; kc += 32) {
    __syncthreads();
    for (int f = t * 4; f < 32 * 128; f += 1024) {
      int kk = f >> 7, col = f & 127;
      *(float4*)&Bs[kk][col] = *(const float4*)(Wm + (size_t)(kc + kk) * 128 + col);
    }
    __syncthreads();
#pragma unroll
    for (int k = 0; k < 32; ++k) {
      float av[4];
#pragma unroll
      for (int r = 0; r < 4; ++r) av[r] = xs[ty * 4 + r][kc + k];
      float4 b0 = *(const float4*)&Bs[k][tx * 8];
      float4 b1 = *(const float4*)&Bs[k][tx * 8 + 4];
      float bv[8] = {b0.x, b0.y, b0.z, b0.w, b1.x, b1.y, b1.z, b1.w};
#pragma unroll
      for (int r = 0; r < 4; ++r)
#pragma unroll
        for (int c = 0; c < 8; ++c) acc[r][c] = fmaf(av[r], bv[c], acc[r][c]);
    }
  }

  float bj[8];
#pragma unroll
  for (int c = 0; c < 8; ++c) bj[c] = bias[tx * 8 + c];
#pragma unroll
  for (int r = 0; r < 4; ++r) {
    int row = r0 + ty * 4 + r;
    if (row < n) {
      float4 o0 = make_float4(acc[r][0] + bj[0], acc[r][1] + bj[1],
                              acc[r][2] + bj[2], acc[r][3] + bj[3]);
      float4 o1 = make_float4(acc[r][4] + bj[4], acc[r][5] + bj[5],
                              acc[r][6] + bj[6], acc[r][7] + bj[7]);
      *(float4*)(io + (size_t)row * 128 + tx * 8 + 0) = o0;
      *(float4*)(io + (size_t)row * 128 + tx * 8 + 4) = o1;
    }
  }
}

extern "C" void kernel_launch(void* const* d_in, const int* in_sizes, int n_in,
                              void* d_out, int out_size, void* d_ws, size_t ws_size,
                              hipStream_t stream) {
  const float* x = (const float*)d_in[0];
  const int* ei = (const int*)d_in[1];   // harness delivers integers as int32
  const float* Wm = (const float*)d_in[2];
  const float* bias = (const float*)d_in[3];
  float* out = (float*)d_out;

  int N = in_sizes[0] / 128;
  int E = in_sizes[1] / 2;

  size_t need = (size_t)N * 16 + 1024 + (size_t)E * 4;
  int nb_n = (N + 255) / 256;
  int nb_e = (E + 255) / 256;

  if (ws_size >= need) {
    char* p = (char*)d_ws;
    int* cnt = (int*)p;        p += (size_t)N * 4;
    int* offs = (int*)p;       p += (size_t)N * 4;
    int* cursor = (int*)p;     p += (size_t)N * 4;
    float* dinv = (float*)p;   p += (size_t)N * 4;
    int* bsums = (int*)p;      p += 1024;
    int* csr = (int*)p;        p += (size_t)E * 4;

    int nb_scan = (N + SCAN_E - 1) / SCAN_E;  // 98 for N=100000 (<=256 required)

    k_init<<<nb_n, 256, 0, stream>>>(cnt, cursor, N);
    k_count<<<nb_e, 256, 0, stream>>>(ei, cnt, E);
    k_scan_local<<<nb_scan, SCAN_T, 0, stream>>>(cnt, offs, bsums, N);
    k_scan_bsums<<<1, SCAN_T, 0, stream>>>(bsums, nb_scan);
    k_scan_add_dinv<<<nb_n, 256, 0, stream>>>(offs, bsums, cnt, dinv, N);
    k_fill<<<nb_e, 256, 0, stream>>>(ei, offs, cursor, csr, E);
    k_aggregate<<<(N + WPB - 1) / WPB, 256, 0, stream>>>(x, dinv, offs, cnt, csr, out, N);
  } else {
    // Small-workspace fallback: atomic scatter (needs 8N bytes)
    char* p = (char*)d_ws;
    int* deg = (int*)p;        p += (size_t)N * 4;
    float* dinv = (float*)p;   p += (size_t)N * 4;
    k_deg_init<<<nb_n, 256, 0, stream>>>(deg, N);
    k_count<<<nb_e, 256, 0, stream>>>(ei, deg, E);
    k_dinv_only<<<nb_n, 256, 0, stream>>>(deg, dinv, N);
    k_self_init<<<(N * 32 + 255) / 256, 256, 0, stream>>>(x, dinv, out, N);
    k_scatter<<<((size_t)E * 32 + 255) / 256, 256, 0, stream>>>(ei, x, dinv, out, E);
  }
  k_gemm_bias<<<(N + 63) / 64, 256, 0, stream>>>(out, Wm, bias, N);
}

// Round 3
// 394.770 us; speedup vs baseline: 1.1275x; 1.1275x over previous
//
#include <hip/hip_runtime.h>

// GCNConv: out = A_hat @ x @ W + b, A_hat = D^-1/2 (A + I) D^-1/2
// v3: h' = dinv * (x @ W) in bf16 via MFMA, CSR gather-sum of bf16 rows,
// final scale by dinv[dst] + bias fused into the aggregate (writes d_out once).

#define SCAN_T 256
#define SCAN_E 1024   // elements scanned per block (4/thread)
#define WPB 4         // nodes (waves) per block in aggregate

typedef __attribute__((ext_vector_type(8))) short short8;
typedef __attribute__((ext_vector_type(4))) float f32x4;

__device__ __forceinline__ unsigned short f2bf(float f) {
  unsigned int u = __float_as_uint(f);
  u += 0x7FFFu + ((u >> 16) & 1u);   // RNE
  return (unsigned short)(u >> 16);
}
__device__ __forceinline__ float bf_lo(unsigned int u) { return __uint_as_float(u << 16); }
__device__ __forceinline__ float bf_hi(unsigned int u) { return __uint_as_float(u & 0xFFFF0000u); }

// ---------------- CSR build ----------------
__global__ void k_init(int* __restrict__ cnt, int n) {
  int i = blockIdx.x * blockDim.x + threadIdx.x;
  if (i < n) cnt[i] = 0;
}

__global__ void k_count4(const int* __restrict__ ei, int* __restrict__ cnt, int E) {
  int i = blockIdx.x * blockDim.x + threadIdx.x;
  int e = i * 4;
  if (e + 3 < E) {
    int4 d = *(const int4*)(ei + E + e);
    atomicAdd(&cnt[d.x], 1); atomicAdd(&cnt[d.y], 1);
    atomicAdd(&cnt[d.z], 1); atomicAdd(&cnt[d.w], 1);
  } else {
    for (; e < E; ++e) atomicAdd(&cnt[ei[E + e]], 1);
  }
}

__global__ void k_scan_local(const int* __restrict__ cnt, int* __restrict__ offs,
                             int* __restrict__ bsums, int n) {
  __shared__ int sh[SCAN_T];
  int t = threadIdx.x;
  int base = blockIdx.x * SCAN_E + t * 4;
  int v0 = 0, v1 = 0, v2 = 0, v3 = 0;
  if (base + 0 < n) v0 = cnt[base + 0];
  if (base + 1 < n) v1 = cnt[base + 1];
  if (base + 2 < n) v2 = cnt[base + 2];
  if (base + 3 < n) v3 = cnt[base + 3];
  int sum = v0 + v1 + v2 + v3;
  sh[t] = sum;
  __syncthreads();
  for (int d = 1; d < SCAN_T; d <<= 1) {
    int xv = (t >= d) ? sh[t - d] : 0;
    __syncthreads();
    sh[t] += xv;
    __syncthreads();
  }
  int run = sh[t] - sum;
  if (base + 0 < n) offs[base + 0] = run; run += v0;
  if (base + 1 < n) offs[base + 1] = run; run += v1;
  if (base + 2 < n) offs[base + 2] = run; run += v2;
  if (base + 3 < n) offs[base + 3] = run;
  if (t == SCAN_T - 1) bsums[blockIdx.x] = sh[t];
}

__global__ void k_scan_bsums(int* __restrict__ bsums, int nb) {
  __shared__ int sh[SCAN_T];
  int t = threadIdx.x;
  int v = (t < nb) ? bsums[t] : 0;
  sh[t] = v;
  __syncthreads();
  for (int d = 1; d < SCAN_T; d <<= 1) {
    int xv = (t >= d) ? sh[t - d] : 0;
    __syncthreads();
    sh[t] += xv;
    __syncthreads();
  }
  if (t < nb) bsums[t] = sh[t] - v;  // exclusive
}

__global__ void k_scan_finish(int* __restrict__ offs, const int* __restrict__ bsums,
                              const int* __restrict__ cnt, int* __restrict__ offs2,
                              float* __restrict__ dinv, int n) {
  int i = blockIdx.x * blockDim.x + threadIdx.x;
  if (i < n) {
    int o = offs[i] + bsums[i / SCAN_E];
    offs[i] = o;
    offs2[i] = o;
    dinv[i] = rsqrtf((float)cnt[i] + 1.0f);  // deg includes self loop
  }
}

__global__ void k_fill4(const int* __restrict__ ei, int* __restrict__ offs2,
                        int* __restrict__ csr, int E) {
  int i = blockIdx.x * blockDim.x + threadIdx.x;
  int e = i * 4;
  if (e + 3 < E) {
    int4 s = *(const int4*)(ei + e);
    int4 d = *(const int4*)(ei + E + e);
    csr[atomicAdd(&offs2[d.x], 1)] = s.x;
    csr[atomicAdd(&offs2[d.y], 1)] = s.y;
    csr[atomicAdd(&offs2[d.z], 1)] = s.z;
    csr[atomicAdd(&offs2[d.w], 1)] = s.w;
  } else {
    for (; e < E; ++e) csr[atomicAdd(&offs2[ei[E + e]], 1)] = ei[e];
  }
}

// ---------------- h' = dinv * (x @ W) in bf16, via MFMA ----------------
// Block: 256 thr = 4 waves, 64 rows. W^T staged bf16 in LDS (pitch 136).
__global__ void __launch_bounds__(256) k_gemm_h(
    const float* __restrict__ x, const float* __restrict__ W,
    const float* __restrict__ dinv, unsigned short* __restrict__ h, int n) {
  __shared__ alignas(16) unsigned short Wt[128][136];
  int t = threadIdx.x;
  // stage: task = (kg, nn): read W[kg*4+i][nn] (lane-consecutive nn -> coalesced),
  // write 4 k-consecutive bf16 to Wt[nn][kg*4] (8B ds_write).
#pragma unroll
  for (int p = 0; p < 16; ++p) {
    int task = p * 256 + t;
    int kg = task >> 7, nn = task & 127;
    float w0 = W[(kg * 4 + 0) * 128 + nn];
    float w1 = W[(kg * 4 + 1) * 128 + nn];
    float w2 = W[(kg * 4 + 2) * 128 + nn];
    float w3 = W[(kg * 4 + 3) * 128 + nn];
    ushort4 u;
    u.x = f2bf(w0); u.y = f2bf(w1); u.z = f2bf(w2); u.w = f2bf(w3);
    *(ushort4*)&Wt[nn][kg * 4] = u;
  }
  __syncthreads();

  int w = t >> 6, lane = t & 63;
  int q = lane >> 4, m = lane & 15;
  int r0 = blockIdx.x * 64 + w * 16;

  f32x4 acc[8];
#pragma unroll
  for (int nt = 0; nt < 8; ++nt) acc[nt] = (f32x4){0.f, 0.f, 0.f, 0.f};

  float dscale[4];
#pragma unroll
  for (int rg = 0; rg < 4; ++rg) {
    int r = r0 + q * 4 + rg;
    dscale[rg] = dinv[r < n ? r : n - 1];
  }

#pragma unroll
  for (int ks = 0; ks < 4; ++ks) {
    int row = r0 + m;
    row = row < n ? row : n - 1;
    const float* xp = x + (size_t)row * 128 + ks * 32 + q * 8;
    float4 a0 = *(const float4*)xp;
    float4 a1 = *(const float4*)(xp + 4);
    short8 af;
    af[0] = (short)f2bf(a0.x); af[1] = (short)f2bf(a0.y);
    af[2] = (short)f2bf(a0.z); af[3] = (short)f2bf(a0.w);
    af[4] = (short)f2bf(a1.x); af[5] = (short)f2bf(a1.y);
    af[6] = (short)f2bf(a1.z); af[7] = (short)f2bf(a1.w);
#pragma unroll
    for (int nt = 0; nt < 8; ++nt) {
      short8 bf = *(const short8*)&Wt[nt * 16 + m][ks * 32 + q * 8];
      acc[nt] = __builtin_amdgcn_mfma_f32_16x16x32_bf16(af, bf, acc[nt], 0, 0, 0);
    }
  }

#pragma unroll
  for (int nt = 0; nt < 8; ++nt)
#pragma unroll
    for (int rg = 0; rg < 4; ++rg) {
      int r = r0 + q * 4 + rg;
      if (r < n) h[(size_t)r * 128 + nt * 16 + m] = f2bf(acc[nt][rg] * dscale[rg]);
    }
}

// ---------------- aggregate bf16 h' rows, scale + bias, write out ----------------
__global__ void __launch_bounds__(256) k_agg_bias(
    const unsigned int* __restrict__ h2, const float* __restrict__ dinv,
    const int* __restrict__ offs, const int* __restrict__ cnt,
    const int* __restrict__ csr, const float* __restrict__ bias,
    float* __restrict__ out, int n) {
  int node = blockIdx.x * WPB + (threadIdx.x >> 6);
  int lane = threadIdx.x & 63;
  if (node >= n) return;
  unsigned int sp = h2[(size_t)node * 64 + lane];  // self term (h' has dinv folded)
  float ax = bf_lo(sp), ay = bf_hi(sp);
  int s = offs[node];
  int end = s + cnt[node];
  for (; s + 8 <= end; s += 8) {
    int i0 = csr[s + 0], i1 = csr[s + 1], i2 = csr[s + 2], i3 = csr[s + 3];
    int i4 = csr[s + 4], i5 = csr[s + 5], i6 = csr[s + 6], i7 = csr[s + 7];
    unsigned int u0 = h2[(size_t)i0 * 64 + lane];
    unsigned int u1 = h2[(size_t)i1 * 64 + lane];
    unsigned int u2 = h2[(size_t)i2 * 64 + lane];
    unsigned int u3 = h2[(size_t)i3 * 64 + lane];
    unsigned int u4 = h2[(size_t)i4 * 64 + lane];
    unsigned int u5 = h2[(size_t)i5 * 64 + lane];
    unsigned int u6 = h2[(size_t)i6 * 64 + lane];
    unsigned int u7 = h2[(size_t)i7 * 64 + lane];
    ax += (bf_lo(u0) + bf_lo(u1)) + (bf_lo(u2) + bf_lo(u3)) +
          (bf_lo(u4) + bf_lo(u5)) + (bf_lo(u6) + bf_lo(u7));
    ay += (bf_hi(u0) + bf_hi(u1)) + (bf_hi(u2) + bf_hi(u3)) +
          (bf_hi(u4) + bf_hi(u5)) + (bf_hi(u6) + bf_hi(u7));
  }
  for (; s < end; ++s) {
    unsigned int u = h2[(size_t)csr[s] * 64 + lane];
    ax += bf_lo(u); ay += bf_hi(u);
  }
  float di = dinv[node];
  float2 bb = ((const float2*)bias)[lane];
  float2 r;
  r.x = fmaf(ax, di, bb.x);
  r.y = fmaf(ay, di, bb.y);
  ((float2*)out)[(size_t)node * 64 + lane] = r;
}

// ---------------- fallback kernels (small workspace) ----------------
__global__ void __launch_bounds__(256) k_aggregate_f32(
    const float* __restrict__ x, const float* __restrict__ dinv,
    const int* __restrict__ offs, const int* __restrict__ cnt,
    const int* __restrict__ csr, float* __restrict__ out, int n) {
  int node = blockIdx.x * WPB + (threadIdx.x >> 6);
  int lane = threadIdx.x & 63;
  if (node >= n) return;
  const float2* __restrict__ x2 = (const float2*)x;
  float di = dinv[node];
  float2 self = x2[(size_t)node * 64 + lane];
  float sw = di * di;
  float ax = self.x * sw, ay = self.y * sw;
  int s = offs[node];
  int end = s + cnt[node];
  for (; s + 4 <= end; s += 4) {
    int i0 = csr[s + 0], i1 = csr[s + 1], i2 = csr[s + 2], i3 = csr[s + 3];
    float2 a0 = x2[(size_t)i0 * 64 + lane];
    float2 a1 = x2[(size_t)i1 * 64 + lane];
    float2 a2 = x2[(size_t)i2 * 64 + lane];
    float2 a3 = x2[(size_t)i3 * 64 + lane];
    float w0 = dinv[i0] * di, w1 = dinv[i1] * di, w2 = dinv[i2] * di, w3 = dinv[i3] * di;
    ax = fmaf(a0.x, w0, ax); ay = fmaf(a0.y, w0, ay);
    ax = fmaf(a1.x, w1, ax); ay = fmaf(a1.y, w1, ay);
    ax = fmaf(a2.x, w2, ax); ay = fmaf(a2.y, w2, ay);
    ax = fmaf(a3.x, w3, ax); ay = fmaf(a3.y, w3, ay);
  }
  for (; s < end; ++s) {
    int i0 = csr[s];
    float2 a0 = x2[(size_t)i0 * 64 + lane];
    float w0 = dinv[i0] * di;
    ax = fmaf(a0.x, w0, ax); ay = fmaf(a0.y, w0, ay);
  }
  float2 r; r.x = ax; r.y = ay;
  ((float2*)out)[(size_t)node * 64 + lane] = r;
}

__global__ void __launch_bounds__(256) k_gemm_bias_inplace(
    float* __restrict__ io, const float* __restrict__ Wm,
    const float* __restrict__ bias, int n) {
  __shared__ float xs[64][129];
  __shared__ float Bs[32][128];
  int t = threadIdx.x;
  int r0 = blockIdx.x * 64;
  for (int f = t * 4; f < 64 * 128; f += 1024) {
    int row = f >> 7, col = f & 127;
    float4 v = make_float4(0.f, 0.f, 0.f, 0.f);
    if (r0 + row < n) v = *(const float4*)(io + (size_t)(r0 + row) * 128 + col);
    xs[row][col + 0] = v.x; xs[row][col + 1] = v.y;
    xs[row][col + 2] = v.z; xs[row][col + 3] = v.w;
  }
  int tx = t & 15, ty = t >> 4;
  float acc[4][8];
#pragma unroll
  for (int r = 0; r < 4; ++r)
#pragma unroll
    for (int c = 0; c < 8; ++c) acc[r][c] = 0.f;
  for (int kc = 0; kc < 128; kc += 32) {
    __syncthreads();
    for (int f = t * 4; f < 32 * 128; f += 1024) {
      int kk = f >> 7, col = f & 127;
      *(float4*)&Bs[kk][col] = *(const float4*)(Wm + (size_t)(kc + kk) * 128 + col);
    }
    __syncthreads();
#pragma unroll
    for (int k = 0; k < 32; ++k) {
      float av[4];
#pragma unroll
      for (int r = 0; r < 4; ++r) av[r] = xs[ty * 4 + r][kc + k];
      float4 b0 = *(const float4*)&Bs[k][tx * 8];
      float4 b1 = *(const float4*)&Bs[k][tx * 8 + 4];
      float bv[8] = {b0.x, b0.y, b0.z, b0.w, b1.x, b1.y, b1.z, b1.w};
#pragma unroll
      for (int r = 0; r < 4; ++r)
#pragma unroll
        for (int c = 0; c < 8; ++c) acc[r][c] = fmaf(av[r], bv[c], acc[r][c]);
    }
  }
  float bj[8];
#pragma unroll
  for (int c = 0; c < 8; ++c) bj[c] = bias[tx * 8 + c];
#pragma unroll
  for (int r = 0; r < 4; ++r) {
    int row = r0 + ty * 4 + r;
    if (row < n) {
      float4 o0 = make_float4(acc[r][0] + bj[0], acc[r][1] + bj[1],
                              acc[r][2] + bj[2], acc[r][3] + bj[3]);
      float4 o1 = make_float4(acc[r][4] + bj[4], acc[r][5] + bj[5],
                              acc[r][6] + bj[6], acc[r][7] + bj[7]);
      *(float4*)(io + (size_t)row * 128 + tx * 8 + 0) = o0;
      *(float4*)(io + (size_t)row * 128 + tx * 8 + 4) = o1;
    }
  }
}

extern "C" void kernel_launch(void* const* d_in, const int* in_sizes, int n_in,
                              void* d_out, int out_size, void* d_ws, size_t ws_size,
                              hipStream_t stream) {
  const float* x = (const float*)d_in[0];
  const int* ei = (const int*)d_in[1];   // harness delivers integers as int32
  const float* Wm = (const float*)d_in[2];
  const float* bias = (const float*)d_in[3];
  float* out = (float*)d_out;

  int N = in_sizes[0] / 128;
  int E = in_sizes[1] / 2;

  char* p = (char*)d_ws;
  int* cnt = (int*)p;        p += (size_t)N * 4;
  int* offs = (int*)p;       p += (size_t)N * 4;
  int* offs2 = (int*)p;      p += (size_t)N * 4;
  float* dinv = (float*)p;   p += (size_t)N * 4;
  int* bsums = (int*)p;      p += 1024;
  int* csr = (int*)p;        p += (size_t)E * 4;
  unsigned short* h = (unsigned short*)p;  // N*128 bf16 = 256N bytes (primary only)

  size_t need_csr = (size_t)N * 16 + 1024 + (size_t)E * 4;
  size_t need_full = need_csr + (size_t)N * 256;

  int nb_n = (N + 255) / 256;
  int nb_e4 = ((E + 3) / 4 + 255) / 256;
  int nb_scan = (N + SCAN_E - 1) / SCAN_E;  // 98 for N=100000 (<=256 required)

  // shared CSR build
  k_init<<<nb_n, 256, 0, stream>>>(cnt, N);
  k_count4<<<nb_e4, 256, 0, stream>>>(ei, cnt, E);
  k_scan_local<<<nb_scan, SCAN_T, 0, stream>>>(cnt, offs, bsums, N);
  k_scan_bsums<<<1, SCAN_T, 0, stream>>>(bsums, nb_scan);
  k_scan_finish<<<nb_n, 256, 0, stream>>>(offs, bsums, cnt, offs2, dinv, N);
  k_fill4<<<nb_e4, 256, 0, stream>>>(ei, offs2, csr, E);

  if (ws_size >= need_full) {
    k_gemm_h<<<(N + 63) / 64, 256, 0, stream>>>(x, Wm, dinv, h, N);
    k_agg_bias<<<(N + WPB - 1) / WPB, 256, 0, stream>>>(
        (const unsigned int*)h, dinv, offs, cnt, csr, bias, out, N);
  } else {
    k_aggregate_f32<<<(N + WPB - 1) / WPB, 256, 0, stream>>>(x, dinv, offs, cnt, csr, out, N);
    k_gemm_bias_inplace<<<(N + 63) / 64, 256, 0, stream>>>(out, Wm, bias, N);
  }
}